// Round 8
// baseline (283.268 us; speedup 1.0000x reference)
//
#include <hip/hip_runtime.h>
#include <stdint.h>

typedef unsigned long long u64;
typedef unsigned int u32;
typedef int v4i __attribute__((ext_vector_type(4)));
typedef int v16i __attribute__((ext_vector_type(16)));

#define B_    32
#define CIN   256
#define COUT  256
#define H_    56
#define W_    56
#define HW    3136            // H_*W_
#define NPOS  100352          // B_*HW
#define NROW  1792            // B_*H_
#define NPACKBLK 784          // (NPOS/2/256) * 4 j-chunks

// ---- workspace layout (bytes) ----
// 0        : Bfrag i8[72*8*64*16]     589824   (MFMA B-operand, fragment-order)
// 589824   : alpha f32[256]           1024
// 590848   : ssum  i32[256]           1024
// 591872   : qsum  u64[256]           2048
// 593920   : xbits u64[NPOS*4]        3211264  (ends 3805184)
// 3805184  : S     s16[NPOS*256] NHWC 51380224 (ends 55185408)

// ---------------- Kernel 1: prep (x bitpack ∪ weight prep), grid-partitioned ----------------
__global__ __launch_bounds__(256) void k_prep(
    const float* __restrict__ x,     // [B, C, H, W]
    const float* __restrict__ wgt,   // [O=256, I=256, 3, 3]
    u64* __restrict__ xbits,         // [NPOS][4]
    int8_t* __restrict__ Bfrag,      // [kk=72][nt=8][lane=64][16]
    float* __restrict__ alpha,
    int* __restrict__ ssum,
    unsigned long long* __restrict__ qsum)
{
    const int tid = threadIdx.x;

    if (blockIdx.x < NPACKBLK) {
        // ---- pack sign(x): 2 positions per thread via float2 ----
        const int j = blockIdx.x / 196;                  // channel chunk
        const int p2 = (blockIdx.x - j * 196) * 256 + tid;
        const int pos0 = p2 * 2;                          // even; HW even -> no b crossing
        const int b = pos0 / HW;
        const int hw = pos0 - b * HW;
        const float* xp = x + (size_t)b * CIN * HW + (size_t)j * 64 * HW + hw;
        u64 b0 = 0, b1 = 0;
#pragma unroll 8
        for (int k = 0; k < 64; ++k) {
            const float2 v = *(const float2*)(xp + (size_t)k * HW);
            b0 |= (u64)(v.x > 0.0f) << k;
            b1 |= (u64)(v.y > 0.0f) << k;
        }
        xbits[(size_t)pos0 * 4 + j] = b0;
        xbits[(size_t)(pos0 + 1) * 4 + j] = b1;
        return;
    }

    // ---- weight prep: mean-center, clip, alpha, Bfrag bytes; zero stats ----
    const int o = blockIdx.x - NPACKBLK;
    const int i = tid;                 // input channel
    const int wave = i >> 6, lane = i & 63;
    __shared__ float sred[4][12];

    if (i == 0) { ssum[o] = 0; qsum[o] = 0ULL; }

    float w9[9];
#pragma unroll
    for (int t = 0; t < 9; ++t) w9[t] = wgt[(o * 256 + i) * 9 + t];

    float m[9];
#pragma unroll
    for (int t = 0; t < 9; ++t) m[t] = w9[t];
#pragma unroll
    for (int s = 1; s < 64; s <<= 1)
#pragma unroll
        for (int t = 0; t < 9; ++t) m[t] += __shfl_xor(m[t], s, 64);
    if (lane == 0) {
#pragma unroll
        for (int t = 0; t < 9; ++t) sred[wave][t] = m[t];
    }
    __syncthreads();
#pragma unroll
    for (int t = 0; t < 9; ++t)
        m[t] = (sred[0][t] + sred[1][t] + sred[2][t] + sred[3][t]) * (1.0f / 256.0f);

    float wc[9];
    float asum = 0.0f;
#pragma unroll
    for (int t = 0; t < 9; ++t) {
        float v = w9[t] - m[t];
        v = fminf(fmaxf(v, -1.0f), 1.0f);
        wc[t] = v;
        asum += fabsf(v);
    }
#pragma unroll
    for (int s = 1; s < 64; s <<= 1) asum += __shfl_xor(asum, s, 64);
    __syncthreads();
    if (lane == 0) sred[wave][9] = asum;
    __syncthreads();
    if (i == 0)
        alpha[o] = (sred[0][9] + sred[1][9] + sred[2][9] + sred[3][9]) * (1.0f / 2304.0f);

    // Bfrag[kk][nt][l][j]: value = sign(wc) for k = kk*32 + (l>>5)*16 + j,
    // tap = k>>8, c = k&255; n = nt*32 + (l&31) = o.
#pragma unroll
    for (int t = 0; t < 9; ++t) {
        const int8_t sv = (wc[t] > 0.0f) ? (int8_t)1 : (int8_t)-1;
        const size_t addr =
            ((size_t)((t * 8 + (i >> 5)) * 8 + (o >> 5)) * 64
             + (size_t)(((i >> 4) & 1) * 32 + (o & 31))) * 16 + (i & 15);
        Bfrag[addr] = sv;
    }
}

// ---------------- Kernel 2: implicit-GEMM i8 MFMA conv -> S (NHWC s16) + stats ----------------
// Block = (b, output-row PAIR): M=128 (2 rows x 64, 112 valid), N=256, K=2304.
// 8 MFMA per wave per kk -> ~290 cyc of pipe work self-covers the depth-1 B
// prefetch; B L2 traffic halves vs 1-row blocks. A staged in LDS as +-1 bytes,
// 4 input rows x 58 cols (wp=0,57 zero-pad; M-pad lanes clamp to col 57).
// Granule rotation (g+wp)&15 breaks the 256B-stride bank pattern.
#define MFMA_I8(acc, a, b) \
    asm volatile("v_mfma_i32_32x32x32_i8 %0, %1, %2, %0" : "+a"(acc) : "v"(a), "v"(b))

__global__ __launch_bounds__(256, 2) void kc_mfma(
    const u64* __restrict__ xbits,
    const int8_t* __restrict__ Bfrag,
    short* __restrict__ S,           // [NPOS][256]
    int* __restrict__ ssum,
    unsigned long long* __restrict__ qsum)
{
    const int blk = blockIdx.x;        // (b, hp) : hp = output row pair
    const int b = blk / 28;
    const int hp = blk - b * 28;
    const int h0 = hp * 2;
    const int tid = threadIdx.x;

    __shared__ u32 ldsb[4 * 58 * 64];  // 59392 B: input rows h0-1 .. h0+2

    for (int it = tid; it < 4 * 58 * 16; it += 256) {
        const int r = it / 928;              // 58*16
        const int rem = it - r * 928;
        const int wp = rem >> 4;
        const int g = rem & 15;
        const int ir = h0 - 1 + r;
        const int w_in = wp - 1;
        const bool inb = (ir >= 0) && (ir < H_) && (w_in >= 0) && (w_in < W_);
        u32 chunk16 = 0;
        if (inb) {
            const u64 word = xbits[((size_t)(b * HW + ir * W_ + w_in)) * 4 + (g >> 2)];
            chunk16 = (u32)(word >> ((g & 3) * 16)) & 0xFFFFu;
        }
        u32 out4[4];
#pragma unroll
        for (int d = 0; d < 4; ++d) {
            const u32 nib = (chunk16 >> (4 * d)) & 0xFu;
            const u32 m1 = (nib * 0x00204081u) & 0x01010101u;   // bit u -> byte u
            const u32 inv = m1 ^ 0x01010101u;
            out4[d] = inb ? (0x01010101u ^ (inv * 0xFEu)) : 0u; // 1->+1, 0->-1, OOB->0
        }
        const int gs = (g + wp) & 15;
        u32* dst = &ldsb[((r * 58 + wp) << 6) + gs * 4];
        dst[0] = out4[0]; dst[1] = out4[1]; dst[2] = out4[2]; dst[3] = out4[3];
    }
    __syncthreads();

    const int m0 = tid & 31;           // M row within 32-tile
    const int lh = (tid >> 5) & 1;     // k-half selector
    const int wv = tid >> 6;           // wave id: N cols 64*wv .. 64*wv+63
    const int8_t* smem = (const int8_t*)ldsb;
    const int8_t* Bp = Bfrag + (size_t)(tid & 63) * 16;

    // mt = row_sel*2 + m_half: output row h0+row_sel, m rows m_half*32 + 0..31
    auto ldA = [&](int kk, int mt) -> v4i {
        const int tap = kk >> 3, s = kk & 7;   // constant after unroll
        const int dh = tap / 3;
        const int dw = tap - dh * 3;
        const int r = dh + (mt >> 1);
        const int wpm = min((mt & 1) * 32 + m0 + dw, 57);
        const int gs = (2 * s + lh + wpm) & 15;
        const int addr = ((r * 58 + wpm) << 8) + (gs << 4);
        return *(const v4i*)(smem + addr);
    };
    auto ldB = [&](int kk, int ntl) -> v4i {
        const size_t off = (size_t)((kk * 8) + wv * 2 + ntl) * 1024;
        return *(const v4i*)(Bp + off);
    };

    v16i acc[4][2];
#pragma unroll
    for (int mt = 0; mt < 4; ++mt)
#pragma unroll
        for (int ntl = 0; ntl < 2; ++ntl) acc[mt][ntl] = (v16i){0};

    v4i A[2][4], Bb[2][2];
#pragma unroll
    for (int mt = 0; mt < 4; ++mt) A[0][mt] = ldA(0, mt);
    Bb[0][0] = ldB(0, 0); Bb[0][1] = ldB(0, 1);

#pragma unroll
    for (int kk = 0; kk < 72; ++kk) {
        const int cur = kk & 1, nxt = cur ^ 1;
        if (kk < 71) {
#pragma unroll
            for (int mt = 0; mt < 4; ++mt) A[nxt][mt] = ldA(kk + 1, mt);
            Bb[nxt][0] = ldB(kk + 1, 0); Bb[nxt][1] = ldB(kk + 1, 1);
        }
#pragma unroll
        for (int mt = 0; mt < 4; ++mt) {
            MFMA_I8(acc[mt][0], A[cur][mt], Bb[cur][0]);
            MFMA_I8(acc[mt][1], A[cur][mt], Bb[cur][1]);
        }
    }

    // drain MFMA pipe before AGPR reads (compiler is blind to asm latency)
#pragma unroll
    for (int mt = 0; mt < 4; ++mt)
        asm volatile("s_nop 7\n\ts_nop 7" : "+a"(acc[mt][0]), "+a"(acc[mt][1]));

    // C/D layout: n = nt*32 + (lane&31); m = (reg&3) + 8*(reg>>2) + 4*lh (+32 if m_half)
    const int n0 = wv * 64 + m0;
    const int n1 = n0 + 32;
    int s0 = 0, s1 = 0, q0 = 0, q1 = 0;

#pragma unroll
    for (int mt = 0; mt < 4; ++mt) {
        const int nreg = (mt & 1) ? 12 : 16;     // m_half=1 covers rows 32..55 only
        const int rowb = b * HW + (h0 + (mt >> 1)) * W_;
        const int mb = (mt & 1) * 32;
#pragma unroll
        for (int reg = 0; reg < 16; ++reg) {
            if (reg < nreg) {
                const int m = mb + (reg & 3) + ((reg >> 2) << 3) + (lh << 2);
                const int v0 = acc[mt][0][reg], v1 = acc[mt][1][reg];
                s0 += v0; q0 += v0 * v0; s1 += v1; q1 += v1 * v1;
                S[(size_t)(rowb + m) * 256 + n0] = (short)v0;
                S[(size_t)(rowb + m) * 256 + n1] = (short)v1;
            }
        }
    }

    s0 += __shfl_xor(s0, 32, 64); q0 += __shfl_xor(q0, 32, 64);
    s1 += __shfl_xor(s1, 32, 64); q1 += __shfl_xor(q1, 32, 64);
    if (lh == 0) {
        atomicAdd(&ssum[n0], s0);
        atomicAdd(&qsum[n0], (unsigned long long)(long long)q0);
        atomicAdd(&ssum[n1], s1);
        atomicAdd(&qsum[n1], (unsigned long long)(long long)q1);
    }
}

// ---------------- Kernel 3: BN finalize + NHWC->NCHW transpose + ReLU ----------------
// One block per (b, c64-group, 64-position chunk): max TLP, single pass.
__global__ __launch_bounds__(256) void kb_apply(
    const short* __restrict__ S,
    const int* __restrict__ ssum,
    const unsigned long long* __restrict__ qsum,
    const float* __restrict__ alpha,
    const float* __restrict__ gamma,
    const float* __restrict__ beta,
    float* __restrict__ out)
{
    const int blk = blockIdx.x;              // ((b*4 + cg)*49 + chunk)
    const int chunk = blk % 49;
    const int bcg = blk / 49;
    const int cg = bcg & 3;
    const int b = bcg >> 2;
    const int c0 = cg * 64;
    const int p0 = chunk * 64;
    const int tid = threadIdx.x;

    __shared__ float s_scale[64], s_shift[64];
    __shared__ u32 lds[64 * 33];             // [p][cpair], stride 33 dwords

    if (tid < 64) {                          // BN finalize for this c-group
        const int o = c0 + tid;
        const double N = (double)NPOS;
        double meanS = (double)ssum[o] / N;
        double varS = (double)qsum[o] / N - meanS * meanS;
        double a = (double)alpha[o];
        double rstd = 1.0 / sqrt(a * a * varS + 1e-5);
        double g = (double)gamma[o];
        s_scale[tid] = (float)(g * a * rstd);
        s_shift[tid] = (float)((double)beta[o] - g * a * meanS * rstd);
        // conv bias cancels exactly in training-mode BN
    }

    // read 64p x 64c: 2048 u32, 8 per thread, full-line coalesced
    const u32* Sp = (const u32*)(S + ((size_t)b * HW + p0) * 256 + c0);
#pragma unroll
    for (int k = 0; k < 8; ++k) {
        const int idx = tid + k * 256;       // 0..2047
        const int p = idx >> 5, cp = idx & 31;
        lds[p * 33 + cp] = Sp[p * 128 + cp];
    }
    __syncthreads();

    // write: lanes = consecutive p -> 256B contiguous stores
    const int pl = tid & 63;
    const int ch4 = tid >> 6;                // 4 groups of 16 channels
    const short* lss = (const short*)lds;
#pragma unroll
    for (int cc = 0; cc < 16; ++cc) {
        const int c = ch4 * 16 + cc;
        const float f = fmaxf(fmaf((float)lss[pl * 66 + c], s_scale[c], s_shift[c]), 0.0f);
        out[((size_t)(b * COUT + c0 + c)) * HW + p0 + pl] = f;
    }
}

extern "C" void kernel_launch(void* const* d_in, const int* in_sizes, int n_in,
                              void* d_out, int out_size, void* d_ws, size_t ws_size,
                              hipStream_t stream) {
    const float* x     = (const float*)d_in[0];   // [32,256,56,56]
    const float* wgt   = (const float*)d_in[1];   // [256,256,3,3]
    // d_in[2] = bias: cancels exactly in BN, unused
    const float* gamma = (const float*)d_in[3];
    const float* beta  = (const float*)d_in[4];
    float* out = (float*)d_out;

    char* ws = (char*)d_ws;
    int8_t* Bfrag = (int8_t*)(ws + 0);
    float* alpha = (float*)(ws + 589824);
    int*   ssum  = (int*)(ws + 590848);
    unsigned long long* qsum = (unsigned long long*)(ws + 591872);
    u64*   xbits = (u64*)(ws + 593920);
    short* Sarr  = (short*)(ws + 3805184);

    k_prep<<<NPACKBLK + 256, 256, 0, stream>>>(x, wgt, xbits, Bfrag, alpha, ssum, qsum);
    kc_mfma<<<32 * 28, 256, 0, stream>>>(xbits, Bfrag, Sarr, ssum, qsum);
    kb_apply<<<32 * 4 * 49, 256, 0, stream>>>(Sarr, ssum, qsum, alpha, gamma, beta, out);
}